// Round 3
// baseline (250.537 us; speedup 1.0000x reference)
//
#include <hip/hip_runtime.h>

#define B_ 8
#define DIM_ 512
#define HEADS_ 8
#define HD_ 64
#define HW_ 1024
#define L_ 77
#define LP_ 80
#define CTX_ 768
#define KV_ 1101
#define KVP_ 1152
// sqrt(SCALE^2 * log2(e)) folded into both q and k: 64^-0.25 * sqrt(1.4426950409)
#define SC_QK 0.42466089f

typedef __attribute__((ext_vector_type(8))) short bf16x8;
typedef __attribute__((ext_vector_type(4))) float f32x4;
typedef __attribute__((ext_vector_type(4))) unsigned short u16x4;

__device__ __forceinline__ unsigned short f2bf(float f) {
  union { float f; unsigned int u; } c; c.f = f;
  unsigned int u = c.u;
  return (unsigned short)((u + 0x7fffu + ((u >> 16) & 1u)) >> 16);
}
__device__ __forceinline__ float bf2f(unsigned short h) {
  union { unsigned int u; float f; } c; c.u = ((unsigned int)h) << 16;
  return c.f;
}

#define GLD_LDS16(gsrc, ldst) \
  __builtin_amdgcn_global_load_lds((const __attribute__((address_space(1))) void*)(gsrc), \
                                   (__attribute__((address_space(3))) void*)(ldst), 16, 0, 0)

// ---------------- converts ----------------
__global__ __launch_bounds__(256) void conv_bf16_k(const float* __restrict__ src,
                                                   unsigned short* __restrict__ dst, int n4) {
  int i = blockIdx.x * 256 + threadIdx.x;
  if (i >= n4) return;
  float4 v = *(const float4*)(src + (size_t)i * 4);
  u16x4 o;
  o[0] = f2bf(v.x); o[1] = f2bf(v.y); o[2] = f2bf(v.z); o[3] = f2bf(v.w);
  *(u16x4*)(dst + (size_t)i * 4) = o;
}

__global__ __launch_bounds__(256) void conv_ctx_k(const float* __restrict__ ctx,
                                                  unsigned short* __restrict__ dst) {
  int i = blockIdx.x * 256 + threadIdx.x;
  int total4 = B_ * LP_ * CTX_ / 4;
  if (i >= total4) return;
  int idx = i * 4;
  int b = idx / (LP_ * CTX_);
  int rem = idx - b * (LP_ * CTX_);
  int l = rem / CTX_;
  int c = rem - l * CTX_;
  float4 v = make_float4(0.f, 0.f, 0.f, 0.f);
  if (l < L_) v = *(const float4*)&ctx[((size_t)b * L_ + l) * CTX_ + c];
  u16x4 o;
  o[0] = f2bf(v.x); o[1] = f2bf(v.y); o[2] = f2bf(v.z); o[3] = f2bf(v.w);
  *(u16x4*)(dst + idx) = o;
}

// zero the KV pad rows (1101..1151): garbage (even NaN) in V pad rows would
// poison PV (0*NaN=NaN); K pad rows are masked to -inf in the last attn tile.
__global__ __launch_bounds__(256) void pad_zero_k(unsigned short* __restrict__ k_s,
                                                  unsigned short* __restrict__ vT) {
  int i = blockIdx.x * 256 + threadIdx.x;
  const int total = 64 * (KVP_ - KV_) * 64;
  if (i >= total) return;
  int bh = i / ((KVP_ - KV_) * 64);
  int rem = i - bh * ((KVP_ - KV_) * 64);
  int row = KV_ + rem / 64;
  int d = rem & 63;
  k_s[((size_t)bh * KVP_ + row) * HD_ + d] = 0;
  vT[((size_t)bh * HD_ + d) * KVP_ + row] = 0;
}

// ---------------- groupnorm (fused stats+normalize+transpose) ----------------
__global__ __launch_bounds__(256) void gnorm_k(const float* __restrict__ x,
                                               const float* __restrict__ gamma,
                                               const float* __restrict__ beta,
                                               unsigned short* __restrict__ xn_t) {
  __shared__ unsigned short xs[16][1032];
  __shared__ float red[8];
  const int tid = threadIdx.x;
  const int b = blockIdx.x >> 5, g = blockIdx.x & 31;
  const float* xp = x + ((size_t)b * DIM_ + g * 16) * HW_;
  float sum = 0.f, ssq = 0.f;
#pragma unroll
  for (int i = 0; i < 16; ++i) {
    float4 v = *(const float4*)&xp[i * HW_ + tid * 4];
    sum += v.x + v.y + v.z + v.w;
    ssq += v.x * v.x + v.y * v.y + v.z * v.z + v.w * v.w;
    xs[i][tid * 4 + 0] = f2bf(v.x);
    xs[i][tid * 4 + 1] = f2bf(v.y);
    xs[i][tid * 4 + 2] = f2bf(v.z);
    xs[i][tid * 4 + 3] = f2bf(v.w);
  }
#pragma unroll
  for (int off = 32; off >= 1; off >>= 1) {
    sum += __shfl_xor(sum, off, 64);
    ssq += __shfl_xor(ssq, off, 64);
  }
  if ((tid & 63) == 0) { red[(tid >> 6) * 2] = sum; red[(tid >> 6) * 2 + 1] = ssq; }
  __syncthreads();
  sum = red[0] + red[2] + red[4] + red[6];
  ssq = red[1] + red[3] + red[5] + red[7];
  float mu = sum * (1.f / 16384.f);
  float rstd = rsqrtf(ssq * (1.f / 16384.f) - mu * mu + 1e-5f);
  float a[16], c[16];
#pragma unroll
  for (int ci = 0; ci < 16; ++ci) {
    float gm = gamma[g * 16 + ci], bt = beta[g * 16 + ci];
    a[ci] = rstd * gm;
    c[ci] = bt - mu * rstd * gm;
  }
#pragma unroll
  for (int t = 0; t < 4; ++t) {
    int hw = tid + t * 256;
    unsigned short tmp[16];
#pragma unroll
    for (int ci = 0; ci < 16; ++ci)
      tmp[ci] = f2bf(bf2f(xs[ci][hw]) * a[ci] + c[ci]);
    unsigned int w[8];
#pragma unroll
    for (int j = 0; j < 8; ++j) w[j] = (unsigned int)tmp[2 * j] | ((unsigned int)tmp[2 * j + 1] << 16);
    unsigned short* dptr = &xn_t[((size_t)b * HW_ + hw) * DIM_ + g * 16];
    *(uint4*)dptr = make_uint4(w[0], w[1], w[2], w[3]);
    *(uint4*)(dptr + 8) = make_uint4(w[4], w[5], w[6], w[7]);
  }
}

// ---------------- GEMM: C[m][n] = sum_k A[m][k]*Bt[n][k], 128x128x64 tiles ----------------
template <int MODE>
__global__ __launch_bounds__(256) void gemm_bt_k(const unsigned short* __restrict__ A,
                                                 const unsigned short* __restrict__ Bt,
                                                 int M, int N, int K,
                                                 const float* __restrict__ bias,
                                                 unsigned short* __restrict__ out_q,
                                                 unsigned short* __restrict__ out_k,
                                                 unsigned short* __restrict__ out_v,
                                                 const float* __restrict__ xres,
                                                 float* __restrict__ outf) {
  __shared__ unsigned short As[128 * 64];
  __shared__ unsigned short Bs[128 * 64];
  const int tid = threadIdx.x;
  const int wid = tid >> 6, lane = tid & 63;
  const int lr = lane & 15, lg = lane >> 4;
  const int ntn = N >> 7;
  const int tm = blockIdx.x / ntn, tn = blockIdx.x - tm * ntn;
  const int m0 = tm << 7, n0 = tn << 7;
  const int wr = wid >> 1, wc = wid & 1;
  f32x4 acc[4][4] = {};
  const int nkt = K >> 6;
  for (int kt = 0; kt < nkt; ++kt) {
    const int k0 = kt << 6;
#pragma unroll
    for (int i = 0; i < 4; ++i) {
      int cA = i * 256 + tid;
      const unsigned short* srcA = A + (size_t)(m0 + (cA >> 3)) * K + k0 + (cA & 7) * 8;
      GLD_LDS16(srcA, As + (size_t)(i * 256 + wid * 64) * 8);
    }
#pragma unroll
    for (int i = 0; i < 4; ++i) {
      int cB = i * 256 + tid;
      const unsigned short* srcB = Bt + (size_t)(n0 + (cB >> 3)) * K + k0 + (cB & 7) * 8;
      GLD_LDS16(srcB, Bs + (size_t)(i * 256 + wid * 64) * 8);
    }
    __syncthreads();
#pragma unroll
    for (int ks = 0; ks < 2; ++ks) {
      bf16x8 af[4], bf[4];
#pragma unroll
      for (int mi = 0; mi < 4; ++mi)
        af[mi] = *(const bf16x8*)&As[(wr * 64 + mi * 16 + lr) * 64 + ks * 32 + lg * 8];
#pragma unroll
      for (int nj = 0; nj < 4; ++nj)
        bf[nj] = *(const bf16x8*)&Bs[(wc * 64 + nj * 16 + lr) * 64 + ks * 32 + lg * 8];
#pragma unroll
      for (int mi = 0; mi < 4; ++mi)
#pragma unroll
        for (int nj = 0; nj < 4; ++nj)
          acc[mi][nj] = __builtin_amdgcn_mfma_f32_16x16x32_bf16(af[mi], bf[nj], acc[mi][nj], 0, 0, 0);
    }
    __syncthreads();
  }
#pragma unroll
  for (int mi = 0; mi < 4; ++mi) {
#pragma unroll
    for (int nj = 0; nj < 4; ++nj) {
#pragma unroll
      for (int r = 0; r < 4; ++r) {
        int row = m0 + wr * 64 + mi * 16 + lg * 4 + r;
        int col = n0 + wc * 64 + nj * 16 + lr;
        float v = acc[mi][nj][r];
        if (MODE == 0) {
          v += bias[col];
          int bb = row >> 10, qi = row & 1023;
          int which = col >> 9, head = (col >> 6) & 7, d = col & 63;
          size_t bh = (size_t)bb * HEADS_ + head;
          if (which == 0)      out_q[(bh * HW_ + qi) * HD_ + d] = f2bf(v * SC_QK);
          else if (which == 1) out_k[(bh * KVP_ + (L_ + qi)) * HD_ + d] = f2bf(v * SC_QK);
          else                 out_v[(bh * HD_ + d) * KVP_ + (L_ + qi)] = f2bf(v);
        } else if (MODE == 1) {
          int bb = row / LP_, l = row - bb * LP_;
          if (l < L_) {
            v += bias[col];
            int which = col >> 9, head = (col >> 6) & 7, d = col & 63;
            size_t bh = (size_t)bb * HEADS_ + head;
            if (which == 0) out_k[(bh * KVP_ + l) * HD_ + d] = f2bf(v * SC_QK);
            else            out_v[(bh * HD_ + d) * KVP_ + l] = f2bf(v);
          }
        } else {
          size_t idx = (size_t)(col >> 10) * (DIM_ * HW_) + (size_t)row * HW_ + (col & 1023);
          outf[idx] = v + bias[row] + xres[idx];
        }
      }
    }
  }
}

// ---------------- flash attention (swapped QK^T + reg-prefetch pipeline) ----------------
#define PSTRIDE 72

// One 64-KV tile. kc = current K tile (resident). If PRE: prefetch K(kt+1) into kn
// right after QK. V(kt) loads are issued at tile top (consumed only after softmax).
template <bool MASK, bool PRE>
__device__ __forceinline__ void tile_body(const unsigned short* __restrict__ kp,
                                          const unsigned short* __restrict__ vp,
                                          int kt, bf16x8 (&kc)[8], bf16x8 (&kn)[8],
                                          const bf16x8 (&qf)[2],
                                          unsigned short* Pw, int lr, int lg,
                                          float& mrun, float& lrun, f32x4 (&acc)[4]) {
  const int k0 = kt * 64;
  // issue V(kt) loads now — consumed after softmax (~300 cyc of latency cover)
  bf16x8 vc[8];
#pragma unroll
  for (int ks = 0; ks < 2; ++ks)
#pragma unroll
    for (int dt = 0; dt < 4; ++dt)
      vc[ks * 4 + dt] = *(const bf16x8*)&vp[(size_t)(dt * 16 + lr) * KVP_ + k0 + ks * 32 + lg * 8];
  // QK^T on resident kc
  f32x4 st[4] = {};
#pragma unroll
  for (int ks = 0; ks < 2; ++ks)
#pragma unroll
    for (int t = 0; t < 4; ++t)
      st[t] = __builtin_amdgcn_mfma_f32_16x16x32_bf16(kc[ks * 4 + t], qf[ks], st[t], 0, 0, 0);
  // prefetch K(kt+1) — consumed at the top of the next tile
  if (PRE) {
    const int k1 = k0 + 64;
#pragma unroll
    for (int ks = 0; ks < 2; ++ks)
#pragma unroll
      for (int t = 0; t < 4; ++t)
        kn[ks * 4 + t] = *(const bf16x8*)&kp[(size_t)(k1 + t * 16 + lr) * HD_ + ks * 32 + lg * 8];
  }
  if (MASK) {
#pragma unroll
    for (int t = 0; t < 4; ++t)
#pragma unroll
      for (int r = 0; r < 4; ++r)
        st[t][r] = (k0 + t * 16 + lg * 4 + r < KV_) ? st[t][r] : -INFINITY;
  }
  // row max: 16 in-lane + 2 shfl
  float t0 = fmaxf(fmaxf(st[0][0], st[0][1]), fmaxf(st[0][2], st[0][3]));
  float t1 = fmaxf(fmaxf(st[1][0], st[1][1]), fmaxf(st[1][2], st[1][3]));
  float t2 = fmaxf(fmaxf(st[2][0], st[2][1]), fmaxf(st[2][2], st[2][3]));
  float t3 = fmaxf(fmaxf(st[3][0], st[3][1]), fmaxf(st[3][2], st[3][3]));
  float mx = fmaxf(fmaxf(t0, t1), fmaxf(t2, t3));
  mx = fmaxf(mx, __shfl_xor(mx, 16, 64));
  mx = fmaxf(mx, __shfl_xor(mx, 32, 64));
  // defer-max (T13)
  if (!__all(mx <= mrun + 8.f)) {
    float mn = fmaxf(mrun, mx);
    float al = exp2f(mrun - mn);
    lrun *= al;
#pragma unroll
    for (int dt = 0; dt < 4; ++dt)
#pragma unroll
      for (int r = 0; r < 4; ++r) acc[dt][r] *= al;
    mrun = mn;
  }
#pragma unroll
  for (int t = 0; t < 4; ++t)
#pragma unroll
    for (int r = 0; r < 4; ++r) st[t][r] = exp2f(st[t][r] - mrun);
  float s0 = (st[0][0] + st[0][1]) + (st[0][2] + st[0][3]);
  float s1 = (st[1][0] + st[1][1]) + (st[1][2] + st[1][3]);
  float s2 = (st[2][0] + st[2][1]) + (st[2][2] + st[2][3]);
  float s3 = (st[3][0] + st[3][1]) + (st[3][2] + st[3][3]);
  float rs = (s0 + s1) + (s2 + s3);
  rs += __shfl_xor(rs, 16, 64);
  rs += __shfl_xor(rs, 32, 64);
  lrun += rs;
  // pack P^T -> [q][k] LDS
#pragma unroll
  for (int t = 0; t < 4; ++t) {
    unsigned int w0, w1;
    asm("v_cvt_pk_bf16_f32 %0, %1, %2" : "=v"(w0) : "v"(st[t][0]), "v"(st[t][1]));
    asm("v_cvt_pk_bf16_f32 %0, %1, %2" : "=v"(w1) : "v"(st[t][2]), "v"(st[t][3]));
    *(uint2*)&Pw[lr * PSTRIDE + t * 16 + lg * 4] = make_uint2(w0, w1);
  }
  // PV: O^T[d][q] += V^T[d][k] · P[q][k]   (vc long in flight by now)
#pragma unroll
  for (int ks = 0; ks < 2; ++ks) {
    bf16x8 pb = *(const bf16x8*)&Pw[lr * PSTRIDE + ks * 32 + lg * 8];
#pragma unroll
    for (int dt = 0; dt < 4; ++dt)
      acc[dt] = __builtin_amdgcn_mfma_f32_16x16x32_bf16(vc[ks * 4 + dt], pb, acc[dt], 0, 0, 0);
  }
}

__global__ __launch_bounds__(256) void attn_k(const unsigned short* __restrict__ q_s,
                                              const unsigned short* __restrict__ k_s,
                                              const unsigned short* __restrict__ vT,
                                              unsigned short* __restrict__ at_s) {
  __shared__ unsigned short P[4][16 * PSTRIDE];
  const int tid = threadIdx.x;
  const int wid = tid >> 6, lane = tid & 63;
  const int lr = lane & 15, lg = lane >> 4;
  // XCD-bijective swizzle: all 16 q-chunks of a (b,head) land on one XCD
  const int bidx = blockIdx.x;
  const int xcd = bidx & 7, idx = bidx >> 3;
  const int bh = xcd + 8 * (idx >> 4);
  const int qt = idx & 15;
  const int q0 = qt * 64 + wid * 16;
  const unsigned short* qp = q_s + (size_t)bh * HW_ * HD_;
  const unsigned short* kp = k_s + (size_t)bh * KVP_ * HD_;
  const unsigned short* vp = vT + (size_t)bh * HD_ * KVP_;
  unsigned short* Pw = P[wid];

  bf16x8 qf[2];
#pragma unroll
  for (int ks = 0; ks < 2; ++ks)
    qf[ks] = *(const bf16x8*)&qp[(size_t)(q0 + lr) * HD_ + ks * 32 + lg * 8];

  f32x4 acc[4] = {};
  float mrun = -INFINITY, lrun = 0.f;

  bf16x8 kc[8], kn[8];
#pragma unroll
  for (int ks = 0; ks < 2; ++ks)
#pragma unroll
    for (int t = 0; t < 4; ++t)
      kc[ks * 4 + t] = *(const bf16x8*)&kp[(size_t)(t * 16 + lr) * HD_ + ks * 32 + lg * 8];

  for (int kt = 0; kt < 17; ++kt) {
    tile_body<false, true>(kp, vp, kt, kc, kn, qf, Pw, lr, lg, mrun, lrun, acc);
#pragma unroll
    for (int i = 0; i < 8; ++i) kc[i] = kn[i];
  }
  tile_body<true, false>(kp, vp, 17, kc, kn, qf, Pw, lr, lg, mrun, lrun, acc);

  const int bb = bh >> 3, head = bh & 7;
  const float inv = 1.f / lrun;
  const int qi = q0 + lr;
#pragma unroll
  for (int dt = 0; dt < 4; ++dt) {
    u16x4 o;
#pragma unroll
    for (int r = 0; r < 4; ++r) o[r] = f2bf(acc[dt][r] * inv);
    *(u16x4*)&at_s[((size_t)bb * HW_ + qi) * DIM_ + head * HD_ + dt * 16 + lg * 4] = o;
  }
}

extern "C" void kernel_launch(void* const* d_in, const int* in_sizes, int n_in,
                              void* d_out, int out_size, void* d_ws, size_t ws_size,
                              hipStream_t stream) {
  (void)in_sizes; (void)n_in; (void)out_size; (void)ws_size;
  const float* x      = (const float*)d_in[0];
  const float* ctx    = (const float*)d_in[1];
  const float* gng    = (const float*)d_in[2];
  const float* gnb    = (const float*)d_in[3];
  const float* qkv_w  = (const float*)d_in[4];
  const float* qkv_b  = (const float*)d_in[5];
  const float* ckv_w  = (const float*)d_in[6];
  const float* ckv_b  = (const float*)d_in[7];
  const float* proj_w = (const float*)d_in[8];
  const float* proj_b = (const float*)d_in[9];
  float* out = (float*)d_out;

  char* ws = (char*)d_ws;
  size_t off = 0;
  auto alloc = [&](size_t bytes) {
    char* p = ws + off;
    off = (off + bytes + 255) & ~(size_t)255;
    return p;
  };
  unsigned short* xn_t    = (unsigned short*)alloc((size_t)B_ * HW_ * DIM_ * 2);
  unsigned short* ctx_bf  = (unsigned short*)alloc((size_t)B_ * LP_ * CTX_ * 2);
  unsigned short* qkvw_bf = (unsigned short*)alloc((size_t)3 * DIM_ * DIM_ * 2);
  unsigned short* ckvw_bf = (unsigned short*)alloc((size_t)2 * DIM_ * CTX_ * 2);
  unsigned short* projw_bf= (unsigned short*)alloc((size_t)DIM_ * DIM_ * 2);
  unsigned short* q_s     = (unsigned short*)alloc((size_t)64 * HW_ * HD_ * 2);
  unsigned short* k_s     = (unsigned short*)alloc((size_t)64 * KVP_ * HD_ * 2);
  unsigned short* vT      = (unsigned short*)alloc((size_t)64 * HD_ * KVP_ * 2);
  unsigned short* at_s    = (unsigned short*)alloc((size_t)B_ * HW_ * DIM_ * 2);

  conv_bf16_k<<<768, 256, 0, stream>>>(qkv_w, qkvw_bf, 3 * DIM_ * DIM_ / 4);
  conv_bf16_k<<<768, 256, 0, stream>>>(ckv_w, ckvw_bf, 2 * DIM_ * CTX_ / 4);
  conv_bf16_k<<<256, 256, 0, stream>>>(proj_w, projw_bf, DIM_ * DIM_ / 4);
  conv_ctx_k<<<480, 256, 0, stream>>>(ctx, ctx_bf);
  gnorm_k<<<256, 256, 0, stream>>>(x, gng, gnb, xn_t);
  pad_zero_k<<<816, 256, 0, stream>>>(k_s, vT);
  gemm_bt_k<0><<<768, 256, 0, stream>>>(xn_t, qkvw_bf, 8192, 1536, 512, qkv_b,
                                        q_s, k_s, vT, nullptr, nullptr);
  gemm_bt_k<1><<<40, 256, 0, stream>>>(ctx_bf, ckvw_bf, 640, 1024, 768, ckv_b,
                                       nullptr, k_s, vT, nullptr, nullptr);
  attn_k<<<1024, 256, 0, stream>>>(q_s, k_s, vT, at_s);
  gemm_bt_k<2><<<256, 256, 0, stream>>>(projw_bf, at_s, 512, 8192, 512, proj_b,
                                        nullptr, nullptr, nullptr, x, out);
}

// Round 4
// 164.033 us; speedup vs baseline: 1.5274x; 1.5274x over previous
//
#include <hip/hip_runtime.h>

#define B_ 8
#define DIM_ 512
#define HEADS_ 8
#define HD_ 64
#define HW_ 1024
#define L_ 77
#define LP_ 80
#define CTX_ 768
#define KV_ 1101
#define KVP_ 1152
// sqrt(SCALE^2 * log2(e)) folded into both q and k: 64^-0.25 * sqrt(1.4426950409)
#define SC_QK 0.42466089f

typedef __attribute__((ext_vector_type(8))) short bf16x8;
typedef __attribute__((ext_vector_type(4))) float f32x4;
typedef __attribute__((ext_vector_type(4))) unsigned short u16x4;

__device__ __forceinline__ unsigned short f2bf(float f) {
  union { float f; unsigned int u; } c; c.f = f;
  unsigned int u = c.u;
  return (unsigned short)((u + 0x7fffu + ((u >> 16) & 1u)) >> 16);
}
__device__ __forceinline__ float bf2f(unsigned short h) {
  union { unsigned int u; float f; } c; c.u = ((unsigned int)h) << 16;
  return c.f;
}

#define GLD_LDS16(gsrc, ldst) \
  __builtin_amdgcn_global_load_lds((const __attribute__((address_space(1))) void*)(gsrc), \
                                   (__attribute__((address_space(3))) void*)(ldst), 16, 0, 0)

// ---------------- converts ----------------
__global__ __launch_bounds__(256) void conv_bf16_k(const float* __restrict__ src,
                                                   unsigned short* __restrict__ dst, int n4) {
  int i = blockIdx.x * 256 + threadIdx.x;
  if (i >= n4) return;
  float4 v = *(const float4*)(src + (size_t)i * 4);
  u16x4 o;
  o[0] = f2bf(v.x); o[1] = f2bf(v.y); o[2] = f2bf(v.z); o[3] = f2bf(v.w);
  *(u16x4*)(dst + (size_t)i * 4) = o;
}

__global__ __launch_bounds__(256) void conv_ctx_k(const float* __restrict__ ctx,
                                                  unsigned short* __restrict__ dst) {
  int i = blockIdx.x * 256 + threadIdx.x;
  int total4 = B_ * LP_ * CTX_ / 4;
  if (i >= total4) return;
  int idx = i * 4;
  int b = idx / (LP_ * CTX_);
  int rem = idx - b * (LP_ * CTX_);
  int l = rem / CTX_;
  int c = rem - l * CTX_;
  float4 v = make_float4(0.f, 0.f, 0.f, 0.f);
  if (l < L_) v = *(const float4*)&ctx[((size_t)b * L_ + l) * CTX_ + c];
  u16x4 o;
  o[0] = f2bf(v.x); o[1] = f2bf(v.y); o[2] = f2bf(v.z); o[3] = f2bf(v.w);
  *(u16x4*)(dst + idx) = o;
}

// zero the KV pad rows (1101..1151): garbage (even NaN) in V pad rows would
// poison PV (0*NaN=NaN); K pad rows are masked to -inf in the last attn tile.
__global__ __launch_bounds__(256) void pad_zero_k(unsigned short* __restrict__ k_s,
                                                  unsigned short* __restrict__ vT) {
  int i = blockIdx.x * 256 + threadIdx.x;
  const int total = 64 * (KVP_ - KV_) * 64;
  if (i >= total) return;
  int bh = i / ((KVP_ - KV_) * 64);
  int rem = i - bh * ((KVP_ - KV_) * 64);
  int row = KV_ + rem / 64;
  int d = rem & 63;
  k_s[((size_t)bh * KVP_ + row) * HD_ + d] = 0;
  vT[((size_t)bh * HD_ + d) * KVP_ + row] = 0;
}

// ---------------- groupnorm (fused stats+normalize+transpose) ----------------
__global__ __launch_bounds__(256) void gnorm_k(const float* __restrict__ x,
                                               const float* __restrict__ gamma,
                                               const float* __restrict__ beta,
                                               unsigned short* __restrict__ xn_t) {
  __shared__ unsigned short xs[16][1032];
  __shared__ float red[8];
  const int tid = threadIdx.x;
  const int b = blockIdx.x >> 5, g = blockIdx.x & 31;
  const float* xp = x + ((size_t)b * DIM_ + g * 16) * HW_;
  float sum = 0.f, ssq = 0.f;
#pragma unroll
  for (int i = 0; i < 16; ++i) {
    float4 v = *(const float4*)&xp[i * HW_ + tid * 4];
    sum += v.x + v.y + v.z + v.w;
    ssq += v.x * v.x + v.y * v.y + v.z * v.z + v.w * v.w;
    xs[i][tid * 4 + 0] = f2bf(v.x);
    xs[i][tid * 4 + 1] = f2bf(v.y);
    xs[i][tid * 4 + 2] = f2bf(v.z);
    xs[i][tid * 4 + 3] = f2bf(v.w);
  }
#pragma unroll
  for (int off = 32; off >= 1; off >>= 1) {
    sum += __shfl_xor(sum, off, 64);
    ssq += __shfl_xor(ssq, off, 64);
  }
  if ((tid & 63) == 0) { red[(tid >> 6) * 2] = sum; red[(tid >> 6) * 2 + 1] = ssq; }
  __syncthreads();
  sum = red[0] + red[2] + red[4] + red[6];
  ssq = red[1] + red[3] + red[5] + red[7];
  float mu = sum * (1.f / 16384.f);
  float rstd = rsqrtf(ssq * (1.f / 16384.f) - mu * mu + 1e-5f);
  float a[16], c[16];
#pragma unroll
  for (int ci = 0; ci < 16; ++ci) {
    float gm = gamma[g * 16 + ci], bt = beta[g * 16 + ci];
    a[ci] = rstd * gm;
    c[ci] = bt - mu * rstd * gm;
  }
#pragma unroll
  for (int t = 0; t < 4; ++t) {
    int hw = tid + t * 256;
    unsigned short tmp[16];
#pragma unroll
    for (int ci = 0; ci < 16; ++ci)
      tmp[ci] = f2bf(bf2f(xs[ci][hw]) * a[ci] + c[ci]);
    unsigned int w[8];
#pragma unroll
    for (int j = 0; j < 8; ++j) w[j] = (unsigned int)tmp[2 * j] | ((unsigned int)tmp[2 * j + 1] << 16);
    unsigned short* dptr = &xn_t[((size_t)b * HW_ + hw) * DIM_ + g * 16];
    *(uint4*)dptr = make_uint4(w[0], w[1], w[2], w[3]);
    *(uint4*)(dptr + 8) = make_uint4(w[4], w[5], w[6], w[7]);
  }
}

// ---------------- GEMM: C[m][n] = sum_k A[m][k]*Bt[n][k], 128x128x64 tiles ----------------
template <int MODE>
__global__ __launch_bounds__(256) void gemm_bt_k(const unsigned short* __restrict__ A,
                                                 const unsigned short* __restrict__ Bt,
                                                 int M, int N, int K,
                                                 const float* __restrict__ bias,
                                                 unsigned short* __restrict__ out_q,
                                                 unsigned short* __restrict__ out_k,
                                                 unsigned short* __restrict__ out_v,
                                                 const float* __restrict__ xres,
                                                 float* __restrict__ outf) {
  __shared__ unsigned short As[128 * 64];
  __shared__ unsigned short Bs[128 * 64];
  const int tid = threadIdx.x;
  const int wid = tid >> 6, lane = tid & 63;
  const int lr = lane & 15, lg = lane >> 4;
  const int ntn = N >> 7;
  const int tm = blockIdx.x / ntn, tn = blockIdx.x - tm * ntn;
  const int m0 = tm << 7, n0 = tn << 7;
  const int wr = wid >> 1, wc = wid & 1;
  f32x4 acc[4][4] = {};
  const int nkt = K >> 6;
  for (int kt = 0; kt < nkt; ++kt) {
    const int k0 = kt << 6;
#pragma unroll
    for (int i = 0; i < 4; ++i) {
      int cA = i * 256 + tid;
      const unsigned short* srcA = A + (size_t)(m0 + (cA >> 3)) * K + k0 + (cA & 7) * 8;
      GLD_LDS16(srcA, As + (size_t)(i * 256 + wid * 64) * 8);
    }
#pragma unroll
    for (int i = 0; i < 4; ++i) {
      int cB = i * 256 + tid;
      const unsigned short* srcB = Bt + (size_t)(n0 + (cB >> 3)) * K + k0 + (cB & 7) * 8;
      GLD_LDS16(srcB, Bs + (size_t)(i * 256 + wid * 64) * 8);
    }
    __syncthreads();
#pragma unroll
    for (int ks = 0; ks < 2; ++ks) {
      bf16x8 af[4], bf[4];
#pragma unroll
      for (int mi = 0; mi < 4; ++mi)
        af[mi] = *(const bf16x8*)&As[(wr * 64 + mi * 16 + lr) * 64 + ks * 32 + lg * 8];
#pragma unroll
      for (int nj = 0; nj < 4; ++nj)
        bf[nj] = *(const bf16x8*)&Bs[(wc * 64 + nj * 16 + lr) * 64 + ks * 32 + lg * 8];
#pragma unroll
      for (int mi = 0; mi < 4; ++mi)
#pragma unroll
        for (int nj = 0; nj < 4; ++nj)
          acc[mi][nj] = __builtin_amdgcn_mfma_f32_16x16x32_bf16(af[mi], bf[nj], acc[mi][nj], 0, 0, 0);
    }
    __syncthreads();
  }
#pragma unroll
  for (int mi = 0; mi < 4; ++mi) {
#pragma unroll
    for (int nj = 0; nj < 4; ++nj) {
#pragma unroll
      for (int r = 0; r < 4; ++r) {
        int row = m0 + wr * 64 + mi * 16 + lg * 4 + r;
        int col = n0 + wc * 64 + nj * 16 + lr;
        float v = acc[mi][nj][r];
        if (MODE == 0) {
          v += bias[col];
          int bb = row >> 10, qi = row & 1023;
          int which = col >> 9, head = (col >> 6) & 7, d = col & 63;
          size_t bh = (size_t)bb * HEADS_ + head;
          if (which == 0)      out_q[(bh * HW_ + qi) * HD_ + d] = f2bf(v * SC_QK);
          else if (which == 1) out_k[(bh * KVP_ + (L_ + qi)) * HD_ + d] = f2bf(v * SC_QK);
          else                 out_v[(bh * HD_ + d) * KVP_ + (L_ + qi)] = f2bf(v);
        } else if (MODE == 1) {
          int bb = row / LP_, l = row - bb * LP_;
          if (l < L_) {
            v += bias[col];
            int which = col >> 9, head = (col >> 6) & 7, d = col & 63;
            size_t bh = (size_t)bb * HEADS_ + head;
            if (which == 0) out_k[(bh * KVP_ + l) * HD_ + d] = f2bf(v * SC_QK);
            else            out_v[(bh * HD_ + d) * KVP_ + l] = f2bf(v);
          }
        } else {
          size_t idx = (size_t)(col >> 10) * (DIM_ * HW_) + (size_t)row * HW_ + (col & 1023);
          outf[idx] = v + bias[row] + xres[idx];
        }
      }
    }
  }
}

// ---------------- flash attention: block-cooperative LDS-staged K/V ----------------
// block = 4 waves = 128 q (each wave 2 q-cols of 16); K/V 64-KV tiles double-
// buffered in LDS via global_load_lds (XOR-swizzled source chunks, linear dest).
#define PSTRIDE 72

// one 64-KV tile; Ksb/Vsb = current LDS buffers [64][64] (chunk-swizzled)
template <bool MASK>
__device__ __forceinline__ void attn_tile64(const unsigned short* __restrict__ Ksb,
                                            const unsigned short* __restrict__ Vsb,
                                            int krem,
                                            const bf16x8 (&qf)[2][2],
                                            unsigned short* __restrict__ Pw0,
                                            unsigned short* __restrict__ Pw1,
                                            int lr, int lg,
                                            const int (&ro)[4], const int (&koff)[2],
                                            float (&mrun)[2], float (&lrun)[2],
                                            f32x4 (&acc)[2][4]) {
  f32x4 st[2][4] = {};
#pragma unroll
  for (int ks = 0; ks < 2; ++ks) {
    bf16x8 kf[4];
#pragma unroll
    for (int t = 0; t < 4; ++t)
      kf[t] = *(const bf16x8*)&Ksb[ro[t] + koff[ks]];
#pragma unroll
    for (int t = 0; t < 4; ++t) {
      st[0][t] = __builtin_amdgcn_mfma_f32_16x16x32_bf16(kf[t], qf[0][ks], st[0][t], 0, 0, 0);
      st[1][t] = __builtin_amdgcn_mfma_f32_16x16x32_bf16(kf[t], qf[1][ks], st[1][t], 0, 0, 0);
    }
  }
  if (MASK) {
#pragma unroll
    for (int c = 0; c < 2; ++c)
#pragma unroll
      for (int t = 0; t < 4; ++t)
#pragma unroll
        for (int r = 0; r < 4; ++r)
          st[c][t][r] = (t * 16 + lg * 4 + r < krem) ? st[c][t][r] : -INFINITY;
  }
#pragma unroll
  for (int c = 0; c < 2; ++c) {
    float t0 = fmaxf(fmaxf(st[c][0][0], st[c][0][1]), fmaxf(st[c][0][2], st[c][0][3]));
    float t1 = fmaxf(fmaxf(st[c][1][0], st[c][1][1]), fmaxf(st[c][1][2], st[c][1][3]));
    float t2 = fmaxf(fmaxf(st[c][2][0], st[c][2][1]), fmaxf(st[c][2][2], st[c][2][3]));
    float t3 = fmaxf(fmaxf(st[c][3][0], st[c][3][1]), fmaxf(st[c][3][2], st[c][3][3]));
    float mx = fmaxf(fmaxf(t0, t1), fmaxf(t2, t3));
    mx = fmaxf(mx, __shfl_xor(mx, 16, 64));
    mx = fmaxf(mx, __shfl_xor(mx, 32, 64));
    // defer-max (T13): rescale only when max grew by > 8 (log2 units)
    if (!__all(mx <= mrun[c] + 8.f)) {
      float mn = fmaxf(mrun[c], mx);
      float al = exp2f(mrun[c] - mn);
      lrun[c] *= al;
#pragma unroll
      for (int dt = 0; dt < 4; ++dt)
#pragma unroll
        for (int r = 0; r < 4; ++r) acc[c][dt][r] *= al;
      mrun[c] = mn;
    }
#pragma unroll
    for (int t = 0; t < 4; ++t)
#pragma unroll
      for (int r = 0; r < 4; ++r) st[c][t][r] = exp2f(st[c][t][r] - mrun[c]);
    float s0 = (st[c][0][0] + st[c][0][1]) + (st[c][0][2] + st[c][0][3]);
    float s1 = (st[c][1][0] + st[c][1][1]) + (st[c][1][2] + st[c][1][3]);
    float s2 = (st[c][2][0] + st[c][2][1]) + (st[c][2][2] + st[c][2][3]);
    float s3 = (st[c][3][0] + st[c][3][1]) + (st[c][3][2] + st[c][3][3]);
    float rs = (s0 + s1) + (s2 + s3);
    rs += __shfl_xor(rs, 16, 64);
    rs += __shfl_xor(rs, 32, 64);
    lrun[c] += rs;
    unsigned short* Pw = c ? Pw1 : Pw0;
#pragma unroll
    for (int t = 0; t < 4; ++t) {
      unsigned int w0, w1;
      asm("v_cvt_pk_bf16_f32 %0, %1, %2" : "=v"(w0) : "v"(st[c][t][0]), "v"(st[c][t][1]));
      asm("v_cvt_pk_bf16_f32 %0, %1, %2" : "=v"(w1) : "v"(st[c][t][2]), "v"(st[c][t][3]));
      *(uint2*)&Pw[lr * PSTRIDE + t * 16 + lg * 4] = make_uint2(w0, w1);
    }
  }
  // PV: O^T[d][q] += V^T[d][k] · P[q][k] ; V fragment shared by both q-cols
#pragma unroll
  for (int ks = 0; ks < 2; ++ks) {
    bf16x8 pb0 = *(const bf16x8*)&Pw0[lr * PSTRIDE + ks * 32 + lg * 8];
    bf16x8 pb1 = *(const bf16x8*)&Pw1[lr * PSTRIDE + ks * 32 + lg * 8];
#pragma unroll
    for (int dt = 0; dt < 4; ++dt) {
      bf16x8 vf = *(const bf16x8*)&Vsb[ro[dt] + koff[ks]];
      acc[0][dt] = __builtin_amdgcn_mfma_f32_16x16x32_bf16(vf, pb0, acc[0][dt], 0, 0, 0);
      acc[1][dt] = __builtin_amdgcn_mfma_f32_16x16x32_bf16(vf, pb1, acc[1][dt], 0, 0, 0);
    }
  }
}

__global__ __launch_bounds__(256, 2) void attn_k(const unsigned short* __restrict__ q_s,
                                                 const unsigned short* __restrict__ k_s,
                                                 const unsigned short* __restrict__ vT,
                                                 unsigned short* __restrict__ at_s) {
  __shared__ unsigned short Ks[2][4096];
  __shared__ unsigned short Vs[2][4096];
  __shared__ unsigned short Pb[4][2][16 * PSTRIDE];
  const int tid = threadIdx.x;
  const int wid = tid >> 6, lane = tid & 63;
  const int lr = lane & 15, lg = lane >> 4;
  // grid = 512: 64 bh x 8 qtiles of 128 q; XCD-bijective swizzle
  const int bidx = blockIdx.x;
  const int xcd = bidx & 7, idx = bidx >> 3;
  const int bh = xcd + 8 * (idx >> 3);
  const int qt = idx & 7;
  const int q0 = qt * 128 + wid * 32;
  const unsigned short* qp = q_s + (size_t)bh * HW_ * HD_;
  const unsigned short* kp = k_s + (size_t)bh * KVP_ * HD_;
  const unsigned short* vp = vT + (size_t)bh * HD_ * KVP_;
  unsigned short* Pw0 = Pb[wid][0];
  unsigned short* Pw1 = Pb[wid][1];

  // staging lane geometry: 8 rows x 8 chunks of 16B per instr; XOR-swizzled source
  const int srow = lane >> 3;
  const int schunk = (lane & 7) ^ srow;

  auto stage = [&](int bufi, int kk) {
#pragma unroll
    for (int jj = 0; jj < 2; ++jj) {
      GLD_LDS16(kp + (size_t)(kk + wid * 16 + jj * 8 + srow) * HD_ + schunk * 8,
                &Ks[bufi][(wid * 2 + jj) * 512]);
      GLD_LDS16(vp + (size_t)(wid * 16 + jj * 8 + srow) * KVP_ + kk + schunk * 8,
                &Vs[bufi][(wid * 2 + jj) * 512]);
    }
  };

  // read-side geometry (swizzle matches the staged chunk permutation)
  int ro[4], koff[2];
#pragma unroll
  for (int t = 0; t < 4; ++t) ro[t] = (t * 16 + lr) * 64;
#pragma unroll
  for (int ks = 0; ks < 2; ++ks) koff[ks] = ((ks * 4 + lg) ^ (lr & 7)) * 8;

  bf16x8 qf[2][2];
#pragma unroll
  for (int c = 0; c < 2; ++c)
#pragma unroll
    for (int ks = 0; ks < 2; ++ks)
      qf[c][ks] = *(const bf16x8*)&qp[(size_t)(q0 + c * 16 + lr) * HD_ + ks * 32 + lg * 8];

  f32x4 acc[2][4] = {};
  float mrun[2] = {-INFINITY, -INFINITY};
  float lrun[2] = {0.f, 0.f};

  stage(0, 0);
  __syncthreads();
  int k0 = 0;
  for (int it = 0; it < 8; ++it) {
    stage(1, k0 + 64);
    attn_tile64<false>(Ks[0], Vs[0], 64, qf, Pw0, Pw1, lr, lg, ro, koff, mrun, lrun, acc);
    __syncthreads();
    stage(0, k0 + 128);
    attn_tile64<false>(Ks[1], Vs[1], 64, qf, Pw0, Pw1, lr, lg, ro, koff, mrun, lrun, acc);
    __syncthreads();
    k0 += 128;
  }
  // k0 = 1024: final two tiles (1024..1087 unmasked, 1088..1151 masked at KV_)
  stage(1, k0 + 64);
  attn_tile64<false>(Ks[0], Vs[0], 64, qf, Pw0, Pw1, lr, lg, ro, koff, mrun, lrun, acc);
  __syncthreads();
  attn_tile64<true>(Ks[1], Vs[1], KV_ - (k0 + 64), qf, Pw0, Pw1, lr, lg, ro, koff, mrun, lrun, acc);

  const int bb = bh >> 3, head = bh & 7;
#pragma unroll
  for (int c = 0; c < 2; ++c) {
    const float inv = 1.f / lrun[c];
    const int qi = q0 + c * 16 + lr;
#pragma unroll
    for (int dt = 0; dt < 4; ++dt) {
      u16x4 o;
#pragma unroll
      for (int r = 0; r < 4; ++r) o[r] = f2bf(acc[c][dt][r] * inv);
      *(u16x4*)&at_s[((size_t)bb * HW_ + qi) * DIM_ + head * HD_ + dt * 16 + lg * 4] = o;
    }
  }
}

extern "C" void kernel_launch(void* const* d_in, const int* in_sizes, int n_in,
                              void* d_out, int out_size, void* d_ws, size_t ws_size,
                              hipStream_t stream) {
  (void)in_sizes; (void)n_in; (void)out_size; (void)ws_size;
  const float* x      = (const float*)d_in[0];
  const float* ctx    = (const float*)d_in[1];
  const float* gng    = (const float*)d_in[2];
  const float* gnb    = (const float*)d_in[3];
  const float* qkv_w  = (const float*)d_in[4];
  const float* qkv_b  = (const float*)d_in[5];
  const float* ckv_w  = (const float*)d_in[6];
  const float* ckv_b  = (const float*)d_in[7];
  const float* proj_w = (const float*)d_in[8];
  const float* proj_b = (const float*)d_in[9];
  float* out = (float*)d_out;

  char* ws = (char*)d_ws;
  size_t off = 0;
  auto alloc = [&](size_t bytes) {
    char* p = ws + off;
    off = (off + bytes + 255) & ~(size_t)255;
    return p;
  };
  unsigned short* xn_t    = (unsigned short*)alloc((size_t)B_ * HW_ * DIM_ * 2);
  unsigned short* ctx_bf  = (unsigned short*)alloc((size_t)B_ * LP_ * CTX_ * 2);
  unsigned short* qkvw_bf = (unsigned short*)alloc((size_t)3 * DIM_ * DIM_ * 2);
  unsigned short* ckvw_bf = (unsigned short*)alloc((size_t)2 * DIM_ * CTX_ * 2);
  unsigned short* projw_bf= (unsigned short*)alloc((size_t)DIM_ * DIM_ * 2);
  unsigned short* q_s     = (unsigned short*)alloc((size_t)64 * HW_ * HD_ * 2);
  unsigned short* k_s     = (unsigned short*)alloc((size_t)64 * KVP_ * HD_ * 2);
  unsigned short* vT      = (unsigned short*)alloc((size_t)64 * HD_ * KVP_ * 2);
  unsigned short* at_s    = (unsigned short*)alloc((size_t)B_ * HW_ * DIM_ * 2);

  conv_bf16_k<<<768, 256, 0, stream>>>(qkv_w, qkvw_bf, 3 * DIM_ * DIM_ / 4);
  conv_bf16_k<<<768, 256, 0, stream>>>(ckv_w, ckvw_bf, 2 * DIM_ * CTX_ / 4);
  conv_bf16_k<<<256, 256, 0, stream>>>(proj_w, projw_bf, DIM_ * DIM_ / 4);
  conv_ctx_k<<<480, 256, 0, stream>>>(ctx, ctx_bf);
  gnorm_k<<<256, 256, 0, stream>>>(x, gng, gnb, xn_t);
  pad_zero_k<<<816, 256, 0, stream>>>(k_s, vT);
  gemm_bt_k<0><<<768, 256, 0, stream>>>(xn_t, qkvw_bf, 8192, 1536, 512, qkv_b,
                                        q_s, k_s, vT, nullptr, nullptr);
  gemm_bt_k<1><<<40, 256, 0, stream>>>(ctx_bf, ckvw_bf, 640, 1024, 768, ckv_b,
                                       nullptr, k_s, vT, nullptr, nullptr);
  attn_k<<<512, 256, 0, stream>>>(q_s, k_s, vT, at_s);
  gemm_bt_k<2><<<256, 256, 0, stream>>>(projw_bf, at_s, 512, 8192, 512, proj_b,
                                        nullptr, nullptr, nullptr, x, out);
}

// Round 5
// 161.981 us; speedup vs baseline: 1.5467x; 1.0127x over previous
//
#include <hip/hip_runtime.h>

#define B_ 8
#define DIM_ 512
#define HEADS_ 8
#define HD_ 64
#define HW_ 1024
#define L_ 77
#define LP_ 80
#define CTX_ 768
#define KV_ 1101
#define KVP_ 1152
// sqrt(SCALE^2 * log2(e)) folded into both q and k: 64^-0.25 * sqrt(1.4426950409)
#define SC_QK 0.42466089f

typedef __attribute__((ext_vector_type(8))) short bf16x8;
typedef __attribute__((ext_vector_type(4))) float f32x4;
typedef __attribute__((ext_vector_type(4))) unsigned short u16x4;

__device__ __forceinline__ unsigned short f2bf(float f) {
  union { float f; unsigned int u; } c; c.f = f;
  unsigned int u = c.u;
  return (unsigned short)((u + 0x7fffu + ((u >> 16) & 1u)) >> 16);
}
__device__ __forceinline__ float bf2f(unsigned short h) {
  union { unsigned int u; float f; } c; c.u = ((unsigned int)h) << 16;
  return c.f;
}

#define GLD_LDS16(gsrc, ldst) \
  __builtin_amdgcn_global_load_lds((const __attribute__((address_space(1))) void*)(gsrc), \
                                   (__attribute__((address_space(3))) void*)(ldst), 16, 0, 0)

// ---------------- converts ----------------
__global__ __launch_bounds__(256) void conv_bf16_k(const float* __restrict__ src,
                                                   unsigned short* __restrict__ dst, int n4) {
  int i = blockIdx.x * 256 + threadIdx.x;
  if (i >= n4) return;
  float4 v = *(const float4*)(src + (size_t)i * 4);
  u16x4 o;
  o[0] = f2bf(v.x); o[1] = f2bf(v.y); o[2] = f2bf(v.z); o[3] = f2bf(v.w);
  *(u16x4*)(dst + (size_t)i * 4) = o;
}

__global__ __launch_bounds__(256) void conv_ctx_k(const float* __restrict__ ctx,
                                                  unsigned short* __restrict__ dst) {
  int i = blockIdx.x * 256 + threadIdx.x;
  int total4 = B_ * LP_ * CTX_ / 4;
  if (i >= total4) return;
  int idx = i * 4;
  int b = idx / (LP_ * CTX_);
  int rem = idx - b * (LP_ * CTX_);
  int l = rem / CTX_;
  int c = rem - l * CTX_;
  float4 v = make_float4(0.f, 0.f, 0.f, 0.f);
  if (l < L_) v = *(const float4*)&ctx[((size_t)b * L_ + l) * CTX_ + c];
  u16x4 o;
  o[0] = f2bf(v.x); o[1] = f2bf(v.y); o[2] = f2bf(v.z); o[3] = f2bf(v.w);
  *(u16x4*)(dst + idx) = o;
}

// zero the KV pad rows (1101..1151): garbage (even NaN) in V pad rows would
// poison PV (0*NaN=NaN); K pad rows are masked to -inf in the last attn tile.
__global__ __launch_bounds__(256) void pad_zero_k(unsigned short* __restrict__ k_s,
                                                  unsigned short* __restrict__ vT) {
  int i = blockIdx.x * 256 + threadIdx.x;
  const int total = 64 * (KVP_ - KV_) * 64;
  if (i >= total) return;
  int bh = i / ((KVP_ - KV_) * 64);
  int rem = i - bh * ((KVP_ - KV_) * 64);
  int row = KV_ + rem / 64;
  int d = rem & 63;
  k_s[((size_t)bh * KVP_ + row) * HD_ + d] = 0;
  vT[((size_t)bh * HD_ + d) * KVP_ + row] = 0;
}

// ---------------- groupnorm (fused stats+normalize+transpose) ----------------
__global__ __launch_bounds__(256) void gnorm_k(const float* __restrict__ x,
                                               const float* __restrict__ gamma,
                                               const float* __restrict__ beta,
                                               unsigned short* __restrict__ xn_t) {
  __shared__ unsigned short xs[16][1032];
  __shared__ float red[8];
  const int tid = threadIdx.x;
  const int b = blockIdx.x >> 5, g = blockIdx.x & 31;
  const float* xp = x + ((size_t)b * DIM_ + g * 16) * HW_;
  float sum = 0.f, ssq = 0.f;
#pragma unroll
  for (int i = 0; i < 16; ++i) {
    float4 v = *(const float4*)&xp[i * HW_ + tid * 4];
    sum += v.x + v.y + v.z + v.w;
    ssq += v.x * v.x + v.y * v.y + v.z * v.z + v.w * v.w;
    xs[i][tid * 4 + 0] = f2bf(v.x);
    xs[i][tid * 4 + 1] = f2bf(v.y);
    xs[i][tid * 4 + 2] = f2bf(v.z);
    xs[i][tid * 4 + 3] = f2bf(v.w);
  }
#pragma unroll
  for (int off = 32; off >= 1; off >>= 1) {
    sum += __shfl_xor(sum, off, 64);
    ssq += __shfl_xor(ssq, off, 64);
  }
  if ((tid & 63) == 0) { red[(tid >> 6) * 2] = sum; red[(tid >> 6) * 2 + 1] = ssq; }
  __syncthreads();
  sum = red[0] + red[2] + red[4] + red[6];
  ssq = red[1] + red[3] + red[5] + red[7];
  float mu = sum * (1.f / 16384.f);
  float rstd = rsqrtf(ssq * (1.f / 16384.f) - mu * mu + 1e-5f);
  float a[16], c[16];
#pragma unroll
  for (int ci = 0; ci < 16; ++ci) {
    float gm = gamma[g * 16 + ci], bt = beta[g * 16 + ci];
    a[ci] = rstd * gm;
    c[ci] = bt - mu * rstd * gm;
  }
#pragma unroll
  for (int t = 0; t < 4; ++t) {
    int hw = tid + t * 256;
    unsigned short tmp[16];
#pragma unroll
    for (int ci = 0; ci < 16; ++ci)
      tmp[ci] = f2bf(bf2f(xs[ci][hw]) * a[ci] + c[ci]);
    unsigned int w[8];
#pragma unroll
    for (int j = 0; j < 8; ++j) w[j] = (unsigned int)tmp[2 * j] | ((unsigned int)tmp[2 * j + 1] << 16);
    unsigned short* dptr = &xn_t[((size_t)b * HW_ + hw) * DIM_ + g * 16];
    *(uint4*)dptr = make_uint4(w[0], w[1], w[2], w[3]);
    *(uint4*)(dptr + 8) = make_uint4(w[4], w[5], w[6], w[7]);
  }
}

// ---------------- GEMM: C[m][n] = sum_k A[m][k]*Bt[n][k] ----------------
// BM x BN tiles, 2x2 waves, double-buffered LDS (T3-min 2-phase: stage(t+1)
// issued before compute(t), one vmcnt(0)+barrier per K-step).
// MODE 0: qkv -> scatter q_s/k_s/vT (+bias, q/k pre-scaled by SC_QK)
// MODE 1: ckv -> scatter k_s/vT (+bias, k pre-scaled), skip pad rows
// MODE 2: proj -> out = acc + bias[row] + x (residual)
template <int MODE, int BM, int BN>
__global__ __launch_bounds__(256, 2) void gemm_bt_k(const unsigned short* __restrict__ A,
                                                    const unsigned short* __restrict__ Bt,
                                                    int M, int N, int K,
                                                    const float* __restrict__ bias,
                                                    unsigned short* __restrict__ out_q,
                                                    unsigned short* __restrict__ out_k,
                                                    unsigned short* __restrict__ out_v,
                                                    const float* __restrict__ xres,
                                                    float* __restrict__ outf) {
  constexpr int MR = BM / 32;  // fragments per wave in m
  constexpr int NR = BN / 32;  // fragments per wave in n
  __shared__ unsigned short As[2][BM * 64];
  __shared__ unsigned short Bs[2][BN * 64];
  const int tid = threadIdx.x;
  const int wid = tid >> 6, lane = tid & 63;
  const int lr = lane & 15, lg = lane >> 4;
  const int ntn = N / BN;
  const int tm = blockIdx.x / ntn, tn = blockIdx.x - tm * ntn;
  const int m0 = tm * BM, n0 = tn * BN;
  const int wr = wid >> 1, wc = wid & 1;
  f32x4 acc[MR][NR] = {};
  const int nkt = K >> 6;

  auto stage = [&](int bi, int k0) {
#pragma unroll
    for (int i = 0; i < BM / 32; ++i) {
      int c = i * 256 + tid;
      GLD_LDS16(A + (size_t)(m0 + (c >> 3)) * K + k0 + (c & 7) * 8,
                &As[bi][(size_t)(i * 256 + wid * 64) * 8]);
    }
#pragma unroll
    for (int i = 0; i < BN / 32; ++i) {
      int c = i * 256 + tid;
      GLD_LDS16(Bt + (size_t)(n0 + (c >> 3)) * K + k0 + (c & 7) * 8,
                &Bs[bi][(size_t)(i * 256 + wid * 64) * 8]);
    }
  };

  stage(0, 0);
  __syncthreads();
  for (int kt = 0; kt < nkt; ++kt) {
    if (kt + 1 < nkt) stage((kt + 1) & 1, (kt + 1) << 6);
    const unsigned short* Ab = As[kt & 1];
    const unsigned short* Bb = Bs[kt & 1];
#pragma unroll
    for (int ks = 0; ks < 2; ++ks) {
      bf16x8 af[MR], bf[NR];
#pragma unroll
      for (int mi = 0; mi < MR; ++mi)
        af[mi] = *(const bf16x8*)&Ab[(wr * (BM / 2) + mi * 16 + lr) * 64 + ks * 32 + lg * 8];
#pragma unroll
      for (int nj = 0; nj < NR; ++nj)
        bf[nj] = *(const bf16x8*)&Bb[(wc * (BN / 2) + nj * 16 + lr) * 64 + ks * 32 + lg * 8];
#pragma unroll
      for (int mi = 0; mi < MR; ++mi)
#pragma unroll
        for (int nj = 0; nj < NR; ++nj)
          acc[mi][nj] = __builtin_amdgcn_mfma_f32_16x16x32_bf16(af[mi], bf[nj], acc[mi][nj], 0, 0, 0);
    }
    __syncthreads();
  }
#pragma unroll
  for (int mi = 0; mi < MR; ++mi) {
#pragma unroll
    for (int nj = 0; nj < NR; ++nj) {
#pragma unroll
      for (int r = 0; r < 4; ++r) {
        int row = m0 + wr * (BM / 2) + mi * 16 + lg * 4 + r;
        int col = n0 + wc * (BN / 2) + nj * 16 + lr;
        float v = acc[mi][nj][r];
        if (MODE == 0) {
          v += bias[col];
          int bb = row >> 10, qi = row & 1023;
          int which = col >> 9, head = (col >> 6) & 7, d = col & 63;
          size_t bh = (size_t)bb * HEADS_ + head;
          if (which == 0)      out_q[(bh * HW_ + qi) * HD_ + d] = f2bf(v * SC_QK);
          else if (which == 1) out_k[(bh * KVP_ + (L_ + qi)) * HD_ + d] = f2bf(v * SC_QK);
          else                 out_v[(bh * HD_ + d) * KVP_ + (L_ + qi)] = f2bf(v);
        } else if (MODE == 1) {
          int bb = row / LP_, l = row - bb * LP_;
          if (l < L_) {
            v += bias[col];
            int which = col >> 9, head = (col >> 6) & 7, d = col & 63;
            size_t bh = (size_t)bb * HEADS_ + head;
            if (which == 0) out_k[(bh * KVP_ + l) * HD_ + d] = f2bf(v * SC_QK);
            else            out_v[(bh * HD_ + d) * KVP_ + l] = f2bf(v);
          }
        } else {
          size_t idx = (size_t)(col >> 10) * (DIM_ * HW_) + (size_t)row * HW_ + (col & 1023);
          outf[idx] = v + bias[row] + xres[idx];
        }
      }
    }
  }
}

// ---------------- flash attention: block-cooperative LDS-staged K/V ----------------
// block = 4 waves = 128 q (each wave 2 q-cols of 16); K/V 64-KV tiles double-
// buffered in LDS via global_load_lds (XOR-swizzled source chunks, linear dest).
#define PSTRIDE 72

// one 64-KV tile; Ksb/Vsb = current LDS buffers [64][64] (chunk-swizzled)
template <bool MASK>
__device__ __forceinline__ void attn_tile64(const unsigned short* __restrict__ Ksb,
                                            const unsigned short* __restrict__ Vsb,
                                            int krem,
                                            const bf16x8 (&qf)[2][2],
                                            unsigned short* __restrict__ Pw0,
                                            unsigned short* __restrict__ Pw1,
                                            int lr, int lg,
                                            const int (&ro)[4], const int (&koff)[2],
                                            float (&mrun)[2], float (&lrun)[2],
                                            f32x4 (&acc)[2][4]) {
  f32x4 st[2][4] = {};
#pragma unroll
  for (int ks = 0; ks < 2; ++ks) {
    bf16x8 kf[4];
#pragma unroll
    for (int t = 0; t < 4; ++t)
      kf[t] = *(const bf16x8*)&Ksb[ro[t] + koff[ks]];
#pragma unroll
    for (int t = 0; t < 4; ++t) {
      st[0][t] = __builtin_amdgcn_mfma_f32_16x16x32_bf16(kf[t], qf[0][ks], st[0][t], 0, 0, 0);
      st[1][t] = __builtin_amdgcn_mfma_f32_16x16x32_bf16(kf[t], qf[1][ks], st[1][t], 0, 0, 0);
    }
  }
  if (MASK) {
#pragma unroll
    for (int c = 0; c < 2; ++c)
#pragma unroll
      for (int t = 0; t < 4; ++t)
#pragma unroll
        for (int r = 0; r < 4; ++r)
          st[c][t][r] = (t * 16 + lg * 4 + r < krem) ? st[c][t][r] : -INFINITY;
  }
#pragma unroll
  for (int c = 0; c < 2; ++c) {
    float t0 = fmaxf(fmaxf(st[c][0][0], st[c][0][1]), fmaxf(st[c][0][2], st[c][0][3]));
    float t1 = fmaxf(fmaxf(st[c][1][0], st[c][1][1]), fmaxf(st[c][1][2], st[c][1][3]));
    float t2 = fmaxf(fmaxf(st[c][2][0], st[c][2][1]), fmaxf(st[c][2][2], st[c][2][3]));
    float t3 = fmaxf(fmaxf(st[c][3][0], st[c][3][1]), fmaxf(st[c][3][2], st[c][3][3]));
    float mx = fmaxf(fmaxf(t0, t1), fmaxf(t2, t3));
    mx = fmaxf(mx, __shfl_xor(mx, 16, 64));
    mx = fmaxf(mx, __shfl_xor(mx, 32, 64));
    // defer-max (T13): rescale only when max grew by > 8 (log2 units)
    if (!__all(mx <= mrun[c] + 8.f)) {
      float mn = fmaxf(mrun[c], mx);
      float al = exp2f(mrun[c] - mn);
      lrun[c] *= al;
#pragma unroll
      for (int dt = 0; dt < 4; ++dt)
#pragma unroll
        for (int r = 0; r < 4; ++r) acc[c][dt][r] *= al;
      mrun[c] = mn;
    }
#pragma unroll
    for (int t = 0; t < 4; ++t)
#pragma unroll
      for (int r = 0; r < 4; ++r) st[c][t][r] = exp2f(st[c][t][r] - mrun[c]);
    float s0 = (st[c][0][0] + st[c][0][1]) + (st[c][0][2] + st[c][0][3]);
    float s1 = (st[c][1][0] + st[c][1][1]) + (st[c][1][2] + st[c][1][3]);
    float s2 = (st[c][2][0] + st[c][2][1]) + (st[c][2][2] + st[c][2][3]);
    float s3 = (st[c][3][0] + st[c][3][1]) + (st[c][3][2] + st[c][3][3]);
    float rs = (s0 + s1) + (s2 + s3);
    rs += __shfl_xor(rs, 16, 64);
    rs += __shfl_xor(rs, 32, 64);
    lrun[c] += rs;
    unsigned short* Pw = c ? Pw1 : Pw0;
#pragma unroll
    for (int t = 0; t < 4; ++t) {
      unsigned int w0, w1;
      asm("v_cvt_pk_bf16_f32 %0, %1, %2" : "=v"(w0) : "v"(st[c][t][0]), "v"(st[c][t][1]));
      asm("v_cvt_pk_bf16_f32 %0, %1, %2" : "=v"(w1) : "v"(st[c][t][2]), "v"(st[c][t][3]));
      *(uint2*)&Pw[lr * PSTRIDE + t * 16 + lg * 4] = make_uint2(w0, w1);
    }
  }
  // PV: O^T[d][q] += V^T[d][k] · P[q][k] ; V fragment shared by both q-cols
#pragma unroll
  for (int ks = 0; ks < 2; ++ks) {
    bf16x8 pb0 = *(const bf16x8*)&Pw0[lr * PSTRIDE + ks * 32 + lg * 8];
    bf16x8 pb1 = *(const bf16x8*)&Pw1[lr * PSTRIDE + ks * 32 + lg * 8];
#pragma unroll
    for (int dt = 0; dt < 4; ++dt) {
      bf16x8 vf = *(const bf16x8*)&Vsb[ro[dt] + koff[ks]];
      acc[0][dt] = __builtin_amdgcn_mfma_f32_16x16x32_bf16(vf, pb0, acc[0][dt], 0, 0, 0);
      acc[1][dt] = __builtin_amdgcn_mfma_f32_16x16x32_bf16(vf, pb1, acc[1][dt], 0, 0, 0);
    }
  }
}

__global__ __launch_bounds__(256, 2) void attn_k(const unsigned short* __restrict__ q_s,
                                                 const unsigned short* __restrict__ k_s,
                                                 const unsigned short* __restrict__ vT,
                                                 unsigned short* __restrict__ at_s) {
  __shared__ unsigned short Ks[2][4096];
  __shared__ unsigned short Vs[2][4096];
  __shared__ unsigned short Pb[4][2][16 * PSTRIDE];
  const int tid = threadIdx.x;
  const int wid = tid >> 6, lane = tid & 63;
  const int lr = lane & 15, lg = lane >> 4;
  // grid = 512: 64 bh x 8 qtiles of 128 q; XCD-bijective swizzle
  const int bidx = blockIdx.x;
  const int xcd = bidx & 7, idx = bidx >> 3;
  const int bh = xcd + 8 * (idx >> 3);
  const int qt = idx & 7;
  const int q0 = qt * 128 + wid * 32;
  const unsigned short* qp = q_s + (size_t)bh * HW_ * HD_;
  const unsigned short* kp = k_s + (size_t)bh * KVP_ * HD_;
  const unsigned short* vp = vT + (size_t)bh * HD_ * KVP_;
  unsigned short* Pw0 = Pb[wid][0];
  unsigned short* Pw1 = Pb[wid][1];

  // staging lane geometry: 8 rows x 8 chunks of 16B per instr; XOR-swizzled source
  const int srow = lane >> 3;
  const int schunk = (lane & 7) ^ srow;

  auto stage = [&](int bufi, int kk) {
#pragma unroll
    for (int jj = 0; jj < 2; ++jj) {
      GLD_LDS16(kp + (size_t)(kk + wid * 16 + jj * 8 + srow) * HD_ + schunk * 8,
                &Ks[bufi][(wid * 2 + jj) * 512]);
      GLD_LDS16(vp + (size_t)(wid * 16 + jj * 8 + srow) * KVP_ + kk + schunk * 8,
                &Vs[bufi][(wid * 2 + jj) * 512]);
    }
  };

  // read-side geometry (swizzle matches the staged chunk permutation)
  int ro[4], koff[2];
#pragma unroll
  for (int t = 0; t < 4; ++t) ro[t] = (t * 16 + lr) * 64;
#pragma unroll
  for (int ks = 0; ks < 2; ++ks) koff[ks] = ((ks * 4 + lg) ^ (lr & 7)) * 8;

  bf16x8 qf[2][2];
#pragma unroll
  for (int c = 0; c < 2; ++c)
#pragma unroll
    for (int ks = 0; ks < 2; ++ks)
      qf[c][ks] = *(const bf16x8*)&qp[(size_t)(q0 + c * 16 + lr) * HD_ + ks * 32 + lg * 8];

  f32x4 acc[2][4] = {};
  float mrun[2] = {-INFINITY, -INFINITY};
  float lrun[2] = {0.f, 0.f};

  stage(0, 0);
  __syncthreads();
  int k0 = 0;
  for (int it = 0; it < 8; ++it) {
    stage(1, k0 + 64);
    attn_tile64<false>(Ks[0], Vs[0], 64, qf, Pw0, Pw1, lr, lg, ro, koff, mrun, lrun, acc);
    __syncthreads();
    stage(0, k0 + 128);
    attn_tile64<false>(Ks[1], Vs[1], 64, qf, Pw0, Pw1, lr, lg, ro, koff, mrun, lrun, acc);
    __syncthreads();
    k0 += 128;
  }
  // k0 = 1024: final two tiles (1024..1087 unmasked, 1088..1151 masked at KV_)
  stage(1, k0 + 64);
  attn_tile64<false>(Ks[0], Vs[0], 64, qf, Pw0, Pw1, lr, lg, ro, koff, mrun, lrun, acc);
  __syncthreads();
  attn_tile64<true>(Ks[1], Vs[1], KV_ - (k0 + 64), qf, Pw0, Pw1, lr, lg, ro, koff, mrun, lrun, acc);

  const int bb = bh >> 3, head = bh & 7;
#pragma unroll
  for (int c = 0; c < 2; ++c) {
    const float inv = 1.f / lrun[c];
    const int qi = q0 + c * 16 + lr;
#pragma unroll
    for (int dt = 0; dt < 4; ++dt) {
      u16x4 o;
#pragma unroll
      for (int r = 0; r < 4; ++r) o[r] = f2bf(acc[c][dt][r] * inv);
      *(u16x4*)&at_s[((size_t)bb * HW_ + qi) * DIM_ + head * HD_ + dt * 16 + lg * 4] = o;
    }
  }
}

extern "C" void kernel_launch(void* const* d_in, const int* in_sizes, int n_in,
                              void* d_out, int out_size, void* d_ws, size_t ws_size,
                              hipStream_t stream) {
  (void)in_sizes; (void)n_in; (void)out_size; (void)ws_size;
  const float* x      = (const float*)d_in[0];
  const float* ctx    = (const float*)d_in[1];
  const float* gng    = (const float*)d_in[2];
  const float* gnb    = (const float*)d_in[3];
  const float* qkv_w  = (const float*)d_in[4];
  const float* qkv_b  = (const float*)d_in[5];
  const float* ckv_w  = (const float*)d_in[6];
  const float* ckv_b  = (const float*)d_in[7];
  const float* proj_w = (const float*)d_in[8];
  const float* proj_b = (const float*)d_in[9];
  float* out = (float*)d_out;

  char* ws = (char*)d_ws;
  size_t off = 0;
  auto alloc = [&](size_t bytes) {
    char* p = ws + off;
    off = (off + bytes + 255) & ~(size_t)255;
    return p;
  };
  unsigned short* xn_t    = (unsigned short*)alloc((size_t)B_ * HW_ * DIM_ * 2);
  unsigned short* ctx_bf  = (unsigned short*)alloc((size_t)B_ * LP_ * CTX_ * 2);
  unsigned short* qkvw_bf = (unsigned short*)alloc((size_t)3 * DIM_ * DIM_ * 2);
  unsigned short* ckvw_bf = (unsigned short*)alloc((size_t)2 * DIM_ * CTX_ * 2);
  unsigned short* projw_bf= (unsigned short*)alloc((size_t)DIM_ * DIM_ * 2);
  unsigned short* q_s     = (unsigned short*)alloc((size_t)64 * HW_ * HD_ * 2);
  unsigned short* k_s     = (unsigned short*)alloc((size_t)64 * KVP_ * HD_ * 2);
  unsigned short* vT      = (unsigned short*)alloc((size_t)64 * HD_ * KVP_ * 2);
  unsigned short* at_s    = (unsigned short*)alloc((size_t)B_ * HW_ * DIM_ * 2);

  conv_bf16_k<<<768, 256, 0, stream>>>(qkv_w, qkvw_bf, 3 * DIM_ * DIM_ / 4);
  conv_bf16_k<<<768, 256, 0, stream>>>(ckv_w, ckvw_bf, 2 * DIM_ * CTX_ / 4);
  conv_bf16_k<<<256, 256, 0, stream>>>(proj_w, projw_bf, DIM_ * DIM_ / 4);
  conv_ctx_k<<<480, 256, 0, stream>>>(ctx, ctx_bf);
  gnorm_k<<<256, 256, 0, stream>>>(x, gng, gnb, xn_t);
  pad_zero_k<<<816, 256, 0, stream>>>(k_s, vT);
  gemm_bt_k<0, 128, 128><<<768, 256, 0, stream>>>(xn_t, qkvw_bf, 8192, 1536, 512, qkv_b,
                                                  q_s, k_s, vT, nullptr, nullptr);
  gemm_bt_k<1, 128, 128><<<40, 256, 0, stream>>>(ctx_bf, ckvw_bf, 640, 1024, 768, ckv_b,
                                                 nullptr, k_s, vT, nullptr, nullptr);
  attn_k<<<512, 256, 0, stream>>>(q_s, k_s, vT, at_s);
  gemm_bt_k<2, 64, 128><<<512, 256, 0, stream>>>(projw_bf, at_s, 512, 8192, 512, proj_b,
                                                 nullptr, nullptr, nullptr, x, out);
}

// Round 6
// 126.488 us; speedup vs baseline: 1.9807x; 1.2806x over previous
//
#include <hip/hip_runtime.h>

#define B_ 8
#define DIM_ 512
#define HEADS_ 8
#define HD_ 64
#define HW_ 1024
#define L_ 77
#define LP_ 80
#define CTX_ 768
#define KV_ 1101
#define KVP_ 1152
// internal KV order: self-attn rows [0,1024), context rows [1024,1101), pad [1101,1152)
#define CTX0_ 1024
// sqrt(SCALE^2 * log2(e)) folded into both q and k: 64^-0.25 * sqrt(1.4426950409)
#define SC_QK 0.42466089f

typedef __attribute__((ext_vector_type(8))) short bf16x8;
typedef __attribute__((ext_vector_type(4))) float f32x4;
typedef __attribute__((ext_vector_type(4))) unsigned short u16x4;

__device__ __forceinline__ unsigned short f2bf(float f) {
  union { float f; unsigned int u; } c; c.f = f;
  unsigned int u = c.u;
  return (unsigned short)((u + 0x7fffu + ((u >> 16) & 1u)) >> 16);
}
__device__ __forceinline__ float bf2f(unsigned short h) {
  union { unsigned int u; float f; } c; c.u = ((unsigned int)h) << 16;
  return c.f;
}

#define GLD_LDS16(gsrc, ldst) \
  __builtin_amdgcn_global_load_lds((const __attribute__((address_space(1))) void*)(gsrc), \
                                   (__attribute__((address_space(3))) void*)(ldst), 16, 0, 0)

// ---------------- converts ----------------
__global__ __launch_bounds__(256) void conv_bf16_k(const float* __restrict__ src,
                                                   unsigned short* __restrict__ dst, int n4) {
  int i = blockIdx.x * 256 + threadIdx.x;
  if (i >= n4) return;
  float4 v = *(const float4*)(src + (size_t)i * 4);
  u16x4 o;
  o[0] = f2bf(v.x); o[1] = f2bf(v.y); o[2] = f2bf(v.z); o[3] = f2bf(v.w);
  *(u16x4*)(dst + (size_t)i * 4) = o;
}

__global__ __launch_bounds__(256) void conv_ctx_k(const float* __restrict__ ctx,
                                                  unsigned short* __restrict__ dst) {
  int i = blockIdx.x * 256 + threadIdx.x;
  int total4 = B_ * LP_ * CTX_ / 4;
  if (i >= total4) return;
  int idx = i * 4;
  int b = idx / (LP_ * CTX_);
  int rem = idx - b * (LP_ * CTX_);
  int l = rem / CTX_;
  int c = rem - l * CTX_;
  float4 v = make_float4(0.f, 0.f, 0.f, 0.f);
  if (l < L_) v = *(const float4*)&ctx[((size_t)b * L_ + l) * CTX_ + c];
  u16x4 o;
  o[0] = f2bf(v.x); o[1] = f2bf(v.y); o[2] = f2bf(v.z); o[3] = f2bf(v.w);
  *(u16x4*)(dst + idx) = o;
}

// zero the KV pad rows (1101..1151)
__global__ __launch_bounds__(256) void pad_zero_k(unsigned short* __restrict__ k_s,
                                                  unsigned short* __restrict__ vT) {
  int i = blockIdx.x * 256 + threadIdx.x;
  const int total = 64 * (KVP_ - KV_) * 64;
  if (i >= total) return;
  int bh = i / ((KVP_ - KV_) * 64);
  int rem = i - bh * ((KVP_ - KV_) * 64);
  int row = KV_ + rem / 64;
  int d = rem & 63;
  k_s[((size_t)bh * KVP_ + row) * HD_ + d] = 0;
  vT[((size_t)bh * HD_ + d) * KVP_ + row] = 0;
}

// ---------------- groupnorm (fused stats+normalize+transpose) ----------------
__global__ __launch_bounds__(256) void gnorm_k(const float* __restrict__ x,
                                               const float* __restrict__ gamma,
                                               const float* __restrict__ beta,
                                               unsigned short* __restrict__ xn_t) {
  __shared__ unsigned short xs[16][1032];
  __shared__ float red[8];
  const int tid = threadIdx.x;
  const int b = blockIdx.x >> 5, g = blockIdx.x & 31;
  const float* xp = x + ((size_t)b * DIM_ + g * 16) * HW_;
  float sum = 0.f, ssq = 0.f;
#pragma unroll
  for (int i = 0; i < 16; ++i) {
    float4 v = *(const float4*)&xp[i * HW_ + tid * 4];
    sum += v.x + v.y + v.z + v.w;
    ssq += v.x * v.x + v.y * v.y + v.z * v.z + v.w * v.w;
    xs[i][tid * 4 + 0] = f2bf(v.x);
    xs[i][tid * 4 + 1] = f2bf(v.y);
    xs[i][tid * 4 + 2] = f2bf(v.z);
    xs[i][tid * 4 + 3] = f2bf(v.w);
  }
#pragma unroll
  for (int off = 32; off >= 1; off >>= 1) {
    sum += __shfl_xor(sum, off, 64);
    ssq += __shfl_xor(ssq, off, 64);
  }
  if ((tid & 63) == 0) { red[(tid >> 6) * 2] = sum; red[(tid >> 6) * 2 + 1] = ssq; }
  __syncthreads();
  sum = red[0] + red[2] + red[4] + red[6];
  ssq = red[1] + red[3] + red[5] + red[7];
  float mu = sum * (1.f / 16384.f);
  float rstd = rsqrtf(ssq * (1.f / 16384.f) - mu * mu + 1e-5f);
  float a[16], c[16];
#pragma unroll
  for (int ci = 0; ci < 16; ++ci) {
    float gm = gamma[g * 16 + ci], bt = beta[g * 16 + ci];
    a[ci] = rstd * gm;
    c[ci] = bt - mu * rstd * gm;
  }
#pragma unroll
  for (int t = 0; t < 4; ++t) {
    int hw = tid + t * 256;
    unsigned short tmp[16];
#pragma unroll
    for (int ci = 0; ci < 16; ++ci)
      tmp[ci] = f2bf(bf2f(xs[ci][hw]) * a[ci] + c[ci]);
    unsigned int w[8];
#pragma unroll
    for (int j = 0; j < 8; ++j) w[j] = (unsigned int)tmp[2 * j] | ((unsigned int)tmp[2 * j + 1] << 16);
    unsigned short* dptr = &xn_t[((size_t)b * HW_ + hw) * DIM_ + g * 16];
    *(uint4*)dptr = make_uint4(w[0], w[1], w[2], w[3]);
    *(uint4*)(dptr + 8) = make_uint4(w[4], w[5], w[6], w[7]);
  }
}

// ---------------- GEMM: C[m][n] = sum_k A[m][k]*Bt[n][k] ----------------
// BM x BN tiles, 2x2 waves, dbuf LDS 2-phase, T2 XOR chunk-swizzle on stage
// source + LDS reads (conflict-free ds_read_b128).
// MODE 0: qkv -> LDS-transpose epilogue, coalesced q/k/v stores (+bias, SC_QK)
// MODE 1: ckv -> scalar scatter to k_s/vT at rows 1024+l
// MODE 2: proj -> out = acc + bias[row] + x (residual), coalesced f32
template <int MODE, int BM, int BN>
__global__ __launch_bounds__(256, 2) void gemm_bt_k(const unsigned short* __restrict__ A,
                                                    const unsigned short* __restrict__ Bt,
                                                    int M, int N, int K,
                                                    const float* __restrict__ bias,
                                                    unsigned short* __restrict__ out_q,
                                                    unsigned short* __restrict__ out_k,
                                                    unsigned short* __restrict__ out_v,
                                                    const float* __restrict__ xres,
                                                    float* __restrict__ outf) {
  constexpr int MR = BM / 32;
  constexpr int NR = BN / 32;
  __shared__ unsigned short sm[2 * (BM + BN) * 64];
  unsigned short* As0 = sm;                 // [2][BM*64]
  unsigned short* Bs0 = sm + 2 * BM * 64;   // [2][BN*64]
  const int tid = threadIdx.x;
  const int wid = tid >> 6, lane = tid & 63;
  const int lr = lane & 15, lg = lane >> 4;
  int bid = blockIdx.x;
  // MODE 0: co-locate same-tm (A-panel-sharing) blocks on one XCD (768 = 8*96)
  if (MODE == 0) bid = (bid & 7) * 96 + (bid >> 3);
  const int ntn = N / BN;
  const int tm = bid / ntn, tn = bid - tm * ntn;
  const int m0 = tm * BM, n0 = tn * BN;
  const int wr = wid >> 1, wc = wid & 1;
  f32x4 acc[MR][NR] = {};
  const int nkt = K >> 6;

  auto stage = [&](int bi, int kk) {
#pragma unroll
    for (int i = 0; i < BM / 32; ++i) {
      int c = i * 256 + tid;
      int row = c >> 3, ch = (c & 7) ^ (row & 7);
      GLD_LDS16(A + (size_t)(m0 + row) * K + kk + ch * 8,
                As0 + (size_t)bi * BM * 64 + (size_t)(i * 256 + wid * 64) * 8);
    }
#pragma unroll
    for (int i = 0; i < BN / 32; ++i) {
      int c = i * 256 + tid;
      int row = c >> 3, ch = (c & 7) ^ (row & 7);
      GLD_LDS16(Bt + (size_t)(n0 + row) * K + kk + ch * 8,
                Bs0 + (size_t)bi * BN * 64 + (size_t)(i * 256 + wid * 64) * 8);
    }
  };

  stage(0, 0);
  __syncthreads();
  for (int kt = 0; kt < nkt; ++kt) {
    if (kt + 1 < nkt) stage((kt + 1) & 1, (kt + 1) << 6);
    const unsigned short* Ab = As0 + (kt & 1) * BM * 64;
    const unsigned short* Bb = Bs0 + (kt & 1) * BN * 64;
#pragma unroll
    for (int ks = 0; ks < 2; ++ks) {
      bf16x8 af[MR], bf[NR];
#pragma unroll
      for (int mi = 0; mi < MR; ++mi)
        af[mi] = *(const bf16x8*)&Ab[(wr * (BM / 2) + mi * 16 + lr) * 64 +
                                     (((ks * 4 + lg) ^ (lr & 7)) * 8)];
#pragma unroll
      for (int nj = 0; nj < NR; ++nj)
        bf[nj] = *(const bf16x8*)&Bb[(wc * (BN / 2) + nj * 16 + lr) * 64 +
                                     (((ks * 4 + lg) ^ (lr & 7)) * 8)];
#pragma unroll
      for (int mi = 0; mi < MR; ++mi)
#pragma unroll
        for (int nj = 0; nj < NR; ++nj)
          acc[mi][nj] = __builtin_amdgcn_mfma_f32_16x16x32_bf16(af[mi], bf[nj], acc[mi][nj], 0, 0, 0);
    }
    __syncthreads();
  }

  if constexpr (MODE == 0) {
    const int which = n0 >> 9;         // uniform per block: 0=q 1=k 2=v
    const int bb = m0 >> 10;
    const int qibase = m0 & 1023;
    if (which == 2) {
      // transpose v through LDS: logical [col 128][qi-chunk 32] of uint2 (4 bf16)
      uint2* Vt = (uint2*)sm;
#pragma unroll
      for (int mi = 0; mi < MR; ++mi) {
#pragma unroll
        for (int nj = 0; nj < NR; ++nj) {
          int col = wc * 64 + nj * 16 + lr;
          float b = bias[n0 + col];
          unsigned int w0, w1;
          float v0 = acc[mi][nj][0] + b, v1 = acc[mi][nj][1] + b;
          float v2 = acc[mi][nj][2] + b, v3 = acc[mi][nj][3] + b;
          asm("v_cvt_pk_bf16_f32 %0, %1, %2" : "=v"(w0) : "v"(v0), "v"(v1));
          asm("v_cvt_pk_bf16_f32 %0, %1, %2" : "=v"(w1) : "v"(v2), "v"(v3));
          int chunk = (wr * 16 + mi * 4 + lg) ^ (lr * 2);
          Vt[col * 32 + chunk] = make_uint2(w0, w1);
        }
      }
      __syncthreads();
#pragma unroll
      for (int it = 0; it < 8; ++it) {
        int col = wid * 32 + it * 4 + lg;
        uint4 val = *(uint4*)&Vt[col * 32 + ((lr * 2) ^ ((col & 15) * 2))];
        int colg = n0 + col;
        int head = (colg >> 6) & 7, d = colg & 63;
        *(uint4*)&out_v[(((size_t)bb * HEADS_ + head) * HD_ + d) * KVP_ + qibase + lr * 8] = val;
      }
    } else {
      // q/k: [qi 128][col 128 (+4 pad)] in LDS, then coalesced 16B row stores
      unsigned short* Tq = sm;
#pragma unroll
      for (int mi = 0; mi < MR; ++mi) {
#pragma unroll
        for (int nj = 0; nj < NR; ++nj) {
          int col = wc * 64 + nj * 16 + lr;
          float b = bias[n0 + col];
          int qr = wr * 64 + mi * 16 + lg * 4;
#pragma unroll
          for (int r = 0; r < 4; ++r)
            Tq[(qr + r) * 132 + col] = f2bf((acc[mi][nj][r] + b) * SC_QK);
        }
      }
      __syncthreads();
#pragma unroll
      for (int it = 0; it < 8; ++it) {
        int qi = wid * 32 + it * 4 + lg;
        uint2 lo = *(uint2*)&Tq[qi * 132 + lr * 8];
        uint2 hi = *(uint2*)&Tq[qi * 132 + lr * 8 + 4];
        uint4 val = make_uint4(lo.x, lo.y, hi.x, hi.y);
        int colg = n0 + lr * 8;
        int head = (colg >> 6) & 7, d = colg & 63;
        size_t bh = (size_t)bb * HEADS_ + head;
        if (which == 0)
          *(uint4*)&out_q[(bh * HW_ + qibase + qi) * HD_ + d] = val;
        else
          *(uint4*)&out_k[(bh * KVP_ + qibase + qi) * HD_ + d] = val;
      }
    }
  } else {
#pragma unroll
    for (int mi = 0; mi < MR; ++mi) {
#pragma unroll
      for (int nj = 0; nj < NR; ++nj) {
#pragma unroll
        for (int r = 0; r < 4; ++r) {
          int row = m0 + wr * (BM / 2) + mi * 16 + lg * 4 + r;
          int col = n0 + wc * (BN / 2) + nj * 16 + lr;
          float v = acc[mi][nj][r];
          if (MODE == 1) {
            int bb = row / LP_, l = row - bb * LP_;
            if (l < L_) {
              v += bias[col];
              int which = col >> 9, head = (col >> 6) & 7, d = col & 63;
              size_t bh = (size_t)bb * HEADS_ + head;
              if (which == 0) out_k[(bh * KVP_ + CTX0_ + l) * HD_ + d] = f2bf(v * SC_QK);
              else            out_v[(bh * HD_ + d) * KVP_ + CTX0_ + l] = f2bf(v);
            }
          } else {
            size_t idx = (size_t)(col >> 10) * (DIM_ * HW_) + (size_t)row * HW_ + (col & 1023);
            outf[idx] = v + bias[row] + xres[idx];
          }
        }
      }
    }
  }
}

// ---------------- flash attention: block-cooperative LDS-staged K/V ----------------
#define PSTRIDE 72

template <bool MASK>
__device__ __forceinline__ void attn_tile64(const unsigned short* __restrict__ Ksb,
                                            const unsigned short* __restrict__ Vsb,
                                            int krem,
                                            const bf16x8 (&qf)[2][2],
                                            unsigned short* __restrict__ Pw0,
                                            unsigned short* __restrict__ Pw1,
                                            int lr, int lg,
                                            const int (&ro)[4], const int (&koff)[2],
                                            float (&mrun)[2], float (&lrun)[2],
                                            f32x4 (&acc)[2][4]) {
  f32x4 st[2][4] = {};
#pragma unroll
  for (int ks = 0; ks < 2; ++ks) {
    bf16x8 kf[4];
#pragma unroll
    for (int t = 0; t < 4; ++t)
      kf[t] = *(const bf16x8*)&Ksb[ro[t] + koff[ks]];
#pragma unroll
    for (int t = 0; t < 4; ++t) {
      st[0][t] = __builtin_amdgcn_mfma_f32_16x16x32_bf16(kf[t], qf[0][ks], st[0][t], 0, 0, 0);
      st[1][t] = __builtin_amdgcn_mfma_f32_16x16x32_bf16(kf[t], qf[1][ks], st[1][t], 0, 0, 0);
    }
  }
  if (MASK) {
#pragma unroll
    for (int c = 0; c < 2; ++c)
#pragma unroll
      for (int t = 0; t < 4; ++t)
#pragma unroll
        for (int r = 0; r < 4; ++r)
          st[c][t][r] = (t * 16 + lg * 4 + r < krem) ? st[c][t][r] : -INFINITY;
  }
#pragma unroll
  for (int c = 0; c < 2; ++c) {
    float t0 = fmaxf(fmaxf(st[c][0][0], st[c][0][1]), fmaxf(st[c][0][2], st[c][0][3]));
    float t1 = fmaxf(fmaxf(st[c][1][0], st[c][1][1]), fmaxf(st[c][1][2], st[c][1][3]));
    float t2 = fmaxf(fmaxf(st[c][2][0], st[c][2][1]), fmaxf(st[c][2][2], st[c][2][3]));
    float t3 = fmaxf(fmaxf(st[c][3][0], st[c][3][1]), fmaxf(st[c][3][2], st[c][3][3]));
    float mx = fmaxf(fmaxf(t0, t1), fmaxf(t2, t3));
    mx = fmaxf(mx, __shfl_xor(mx, 16, 64));
    mx = fmaxf(mx, __shfl_xor(mx, 32, 64));
    if (!__all(mx <= mrun[c] + 8.f)) {
      float mn = fmaxf(mrun[c], mx);
      float al = exp2f(mrun[c] - mn);
      lrun[c] *= al;
#pragma unroll
      for (int dt = 0; dt < 4; ++dt)
#pragma unroll
        for (int r = 0; r < 4; ++r) acc[c][dt][r] *= al;
      mrun[c] = mn;
    }
#pragma unroll
    for (int t = 0; t < 4; ++t)
#pragma unroll
      for (int r = 0; r < 4; ++r) st[c][t][r] = exp2f(st[c][t][r] - mrun[c]);
    float s0 = (st[c][0][0] + st[c][0][1]) + (st[c][0][2] + st[c][0][3]);
    float s1 = (st[c][1][0] + st[c][1][1]) + (st[c][1][2] + st[c][1][3]);
    float s2 = (st[c][2][0] + st[c][2][1]) + (st[c][2][2] + st[c][2][3]);
    float s3 = (st[c][3][0] + st[c][3][1]) + (st[c][3][2] + st[c][3][3]);
    float rs = (s0 + s1) + (s2 + s3);
    rs += __shfl_xor(rs, 16, 64);
    rs += __shfl_xor(rs, 32, 64);
    lrun[c] += rs;
    unsigned short* Pw = c ? Pw1 : Pw0;
#pragma unroll
    for (int t = 0; t < 4; ++t) {
      unsigned int w0, w1;
      asm("v_cvt_pk_bf16_f32 %0, %1, %2" : "=v"(w0) : "v"(st[c][t][0]), "v"(st[c][t][1]));
      asm("v_cvt_pk_bf16_f32 %0, %1, %2" : "=v"(w1) : "v"(st[c][t][2]), "v"(st[c][t][3]));
      *(uint2*)&Pw[lr * PSTRIDE + t * 16 + lg * 4] = make_uint2(w0, w1);
    }
  }
#pragma unroll
  for (int ks = 0; ks < 2; ++ks) {
    bf16x8 pb0 = *(const bf16x8*)&Pw0[lr * PSTRIDE + ks * 32 + lg * 8];
    bf16x8 pb1 = *(const bf16x8*)&Pw1[lr * PSTRIDE + ks * 32 + lg * 8];
#pragma unroll
    for (int dt = 0; dt < 4; ++dt) {
      bf16x8 vf = *(const bf16x8*)&Vsb[ro[dt] + koff[ks]];
      acc[0][dt] = __builtin_amdgcn_mfma_f32_16x16x32_bf16(vf, pb0, acc[0][dt], 0, 0, 0);
      acc[1][dt] = __builtin_amdgcn_mfma_f32_16x16x32_bf16(vf, pb1, acc[1][dt], 0, 0, 0);
    }
  }
}

__global__ __launch_bounds__(256, 2) void attn_k(const unsigned short* __restrict__ q_s,
                                                 const unsigned short* __restrict__ k_s,
                                                 const unsigned short* __restrict__ vT,
                                                 unsigned short* __restrict__ at_s) {
  __shared__ unsigned short Ks[2][4096];
  __shared__ unsigned short Vs[2][4096];
  __shared__ unsigned short Pb[4][2][16 * PSTRIDE];
  const int tid = threadIdx.x;
  const int wid = tid >> 6, lane = tid & 63;
  const int lr = lane & 15, lg = lane >> 4;
  const int bidx = blockIdx.x;
  const int xcd = bidx & 7, idx = bidx >> 3;
  const int bh = xcd + 8 * (idx >> 3);
  const int qt = idx & 7;
  const int q0 = qt * 128 + wid * 32;
  const unsigned short* qp = q_s + (size_t)bh * HW_ * HD_;
  const unsigned short* kp = k_s + (size_t)bh * KVP_ * HD_;
  const unsigned short* vp = vT + (size_t)bh * HD_ * KVP_;
  unsigned short* Pw0 = Pb[wid][0];
  unsigned short* Pw1 = Pb[wid][1];

  const int srow = lane >> 3;
  const int schunk = (lane & 7) ^ srow;

  auto stage = [&](int bufi, int kk) {
#pragma unroll
    for (int jj = 0; jj < 2; ++jj) {
      GLD_LDS16(kp + (size_t)(kk + wid * 16 + jj * 8 + srow) * HD_ + schunk * 8,
                &Ks[bufi][(wid * 2 + jj) * 512]);
      GLD_LDS16(vp + (size_t)(wid * 16 + jj * 8 + srow) * KVP_ + kk + schunk * 8,
                &Vs[bufi][(wid * 2 + jj) * 512]);
    }
  };

  int ro[4], koff[2];
#pragma unroll
  for (int t = 0; t < 4; ++t) ro[t] = (t * 16 + lr) * 64;
#pragma unroll
  for (int ks = 0; ks < 2; ++ks) koff[ks] = ((ks * 4 + lg) ^ (lr & 7)) * 8;

  bf16x8 qf[2][2];
#pragma unroll
  for (int c = 0; c < 2; ++c)
#pragma unroll
    for (int ks = 0; ks < 2; ++ks)
      qf[c][ks] = *(const bf16x8*)&qp[(size_t)(q0 + c * 16 + lr) * HD_ + ks * 32 + lg * 8];

  f32x4 acc[2][4] = {};
  float mrun[2] = {-INFINITY, -INFINITY};
  float lrun[2] = {0.f, 0.f};

  stage(0, 0);
  __syncthreads();
  int k0 = 0;
  for (int it = 0; it < 8; ++it) {
    stage(1, k0 + 64);
    attn_tile64<false>(Ks[0], Vs[0], 64, qf, Pw0, Pw1, lr, lg, ro, koff, mrun, lrun, acc);
    __syncthreads();
    stage(0, k0 + 128);
    attn_tile64<false>(Ks[1], Vs[1], 64, qf, Pw0, Pw1, lr, lg, ro, koff, mrun, lrun, acc);
    __syncthreads();
    k0 += 128;
  }
  stage(1, k0 + 64);
  attn_tile64<false>(Ks[0], Vs[0], 64, qf, Pw0, Pw1, lr, lg, ro, koff, mrun, lrun, acc);
  __syncthreads();
  attn_tile64<true>(Ks[1], Vs[1], KV_ - (k0 + 64), qf, Pw0, Pw1, lr, lg, ro, koff, mrun, lrun, acc);

  const int bb = bh >> 3, head = bh & 7;
#pragma unroll
  for (int c = 0; c < 2; ++c) {
    const float inv = 1.f / lrun[c];
    const int qi = q0 + c * 16 + lr;
#pragma unroll
    for (int dt = 0; dt < 4; ++dt) {
      u16x4 o;
#pragma unroll
      for (int r = 0; r < 4; ++r) o[r] = f2bf(acc[c][dt][r] * inv);
      *(u16x4*)&at_s[((size_t)bb * HW_ + qi) * DIM_ + head * HD_ + dt * 16 + lg * 4] = o;
    }
  }
}

extern "C" void kernel_launch(void* const* d_in, const int* in_sizes, int n_in,
                              void* d_out, int out_size, void* d_ws, size_t ws_size,
                              hipStream_t stream) {
  (void)in_sizes; (void)n_in; (void)out_size; (void)ws_size;
  const float* x      = (const float*)d_in[0];
  const float* ctx    = (const float*)d_in[1];
  const float* gng    = (const float*)d_in[2];
  const float* gnb    = (const float*)d_in[3];
  const float* qkv_w  = (const float*)d_in[4];
  const float* qkv_b  = (const float*)d_in[5];
  const float* ckv_w  = (const float*)d_in[6];
  const float* ckv_b  = (const float*)d_in[7];
  const float* proj_w = (const float*)d_in[8];
  const float* proj_b = (const float*)d_in[9];
  float* out = (float*)d_out;

  char* ws = (char*)d_ws;
  size_t off = 0;
  auto alloc = [&](size_t bytes) {
    char* p = ws + off;
    off = (off + bytes + 255) & ~(size_t)255;
    return p;
  };
  unsigned short* xn_t    = (unsigned short*)alloc((size_t)B_ * HW_ * DIM_ * 2);
  unsigned short* ctx_bf  = (unsigned short*)alloc((size_t)B_ * LP_ * CTX_ * 2);
  unsigned short* qkvw_bf = (unsigned short*)alloc((size_t)3 * DIM_ * DIM_ * 2);
  unsigned short* ckvw_bf = (unsigned short*)alloc((size_t)2 * DIM_ * CTX_ * 2);
  unsigned short* projw_bf= (unsigned short*)alloc((size_t)DIM_ * DIM_ * 2);
  unsigned short* q_s     = (unsigned short*)alloc((size_t)64 * HW_ * HD_ * 2);
  unsigned short* k_s     = (unsigned short*)alloc((size_t)64 * KVP_ * HD_ * 2);
  unsigned short* vT      = (unsigned short*)alloc((size_t)64 * HD_ * KVP_ * 2);
  unsigned short* at_s    = (unsigned short*)alloc((size_t)B_ * HW_ * DIM_ * 2);

  conv_bf16_k<<<768, 256, 0, stream>>>(qkv_w, qkvw_bf, 3 * DIM_ * DIM_ / 4);
  conv_bf16_k<<<768, 256, 0, stream>>>(ckv_w, ckvw_bf, 2 * DIM_ * CTX_ / 4);
  conv_bf16_k<<<256, 256, 0, stream>>>(proj_w, projw_bf, DIM_ * DIM_ / 4);
  conv_ctx_k<<<480, 256, 0, stream>>>(ctx, ctx_bf);
  gnorm_k<<<256, 256, 0, stream>>>(x, gng, gnb, xn_t);
  pad_zero_k<<<816, 256, 0, stream>>>(k_s, vT);
  gemm_bt_k<0, 128, 128><<<768, 256, 0, stream>>>(xn_t, qkvw_bf, 8192, 1536, 512, qkv_b,
                                                  q_s, k_s, vT, nullptr, nullptr);
  gemm_bt_k<1, 128, 128><<<40, 256, 0, stream>>>(ctx_bf, ckvw_bf, 640, 1024, 768, ckv_b,
                                                 nullptr, k_s, vT, nullptr, nullptr);
  attn_k<<<512, 256, 0, stream>>>(q_s, k_s, vT, at_s);
  gemm_bt_k<2, 64, 128><<<512, 256, 0, stream>>>(projw_bf, at_s, 512, 8192, 512, proj_b,
                                                 nullptr, nullptr, nullptr, x, out);
}